// Round 8
// baseline (615.029 us; speedup 1.0000x reference)
//
#include <hip/hip_runtime.h>
#include <cstdint>
#include <cstddef>

#define D_DIM 2048
#define D_HID 8192
#define N_TOK 8192

typedef int v4i __attribute__((ext_vector_type(4)));
typedef float v4f __attribute__((ext_vector_type(4)));

__device__ __forceinline__ void gload16(const void* g, void* l) {
  __builtin_amdgcn_global_load_lds(
      (__attribute__((address_space(1))) void*)(void*)(const_cast<void*>(g)),
      (__attribute__((address_space(3))) void*)(void*)(l), 16, 0, 0);
}

__device__ __forceinline__ unsigned pack4i8(int a, int b, int c, int d) {
  return (unsigned)(a & 255) | ((unsigned)(b & 255) << 8) |
         ((unsigned)(c & 255) << 16) | ((unsigned)(d & 255) << 24);
}

__device__ __forceinline__ int clampi(int v, int lo, int hi) {
  return v < lo ? lo : (v > hi ? hi : v);
}

// Branch-free exact-GELU via Abramowitz-Stegun 7.1.26 erf (|eps| <= 1.5e-7 abs).
__device__ __forceinline__ float gelu_fast(float c) {
  const float ax = fabsf(c) * 0.70710678118654752440f;
  const float t = 1.0f / fmaf(0.3275911f, ax, 1.0f);
  const float poly =
      t * fmaf(t, fmaf(t, fmaf(t, fmaf(t, 1.061405429f, -1.453152027f),
                               1.421413741f), -0.284496736f), 0.254829592f);
  const float e = 1.0f - poly * __expf(-ax * ax);
  const float es = copysignf(e, c);
  return 0.5f * c * (1.0f + es);
}

// ---------------- weight |w| sum (fixed-order f64, deterministic) ------------
__global__ __launch_bounds__(256) void wsum_k(const float* __restrict__ w1,
                                              const float* __restrict__ w2,
                                              double* __restrict__ part) {
  const int b = blockIdx.x;
  const float* w = (b < 1024) ? w1 : w2;
  const size_t base = (size_t)(b & 1023) * 16384;
  const int t = threadIdx.x;
  double s = 0.0;
  for (int i = 0; i < 64; ++i) s += fabs((double)w[base + (size_t)i * 256 + t]);
  __shared__ double red[256];
  red[t] = s;
  __syncthreads();
  for (int st = 128; st; st >>= 1) {
    if (t < st) red[t] += red[t + st];
    __syncthreads();
  }
  if (!t) part[b] = red[0];
}

__global__ __launch_bounds__(256) void wfinal_k(const double* __restrict__ part,
                                                double* __restrict__ swd,
                                                float* __restrict__ wsc) {
  __shared__ double red[256];
  const int t = threadIdx.x;
  for (int m = 0; m < 2; ++m) {
    double s = part[m * 1024 + t] + part[m * 1024 + 256 + t] +
               part[m * 1024 + 512 + t] + part[m * 1024 + 768 + t];
    red[t] = s;
    __syncthreads();
    for (int st = 128; st; st >>= 1) {
      if (t < st) red[t] += red[t + st];
      __syncthreads();
    }
    if (!t) {
      double mean = red[0] / 16777216.0;
      double m2 = fmax(mean, 1e-5);
      swd[m] = 1.0 / m2;
      wsc[m] = (float)m2;
    }
    __syncthreads();
  }
}

// ---------------- ternary weight quant (f64 decision, half-even) -------------
__global__ __launch_bounds__(256) void wquant_k(const float* __restrict__ w,
                                                int8_t* __restrict__ q,
                                                const double* __restrict__ swd, int idx) {
  const double s = swd[idx];
  const size_t i = ((size_t)blockIdx.x * 256 + threadIdx.x) * 4;
  const float4 v = *(const float4*)&w[i];
  const int q0 = clampi((int)__builtin_rint((double)v.x * s), -1, 1);
  const int q1 = clampi((int)__builtin_rint((double)v.y * s), -1, 1);
  const int q2 = clampi((int)__builtin_rint((double)v.z * s), -1, 1);
  const int q3 = clampi((int)__builtin_rint((double)v.w * s), -1, 1);
  *(unsigned*)&q[i] = pack4i8(q0, q1, q2, q3);
}

// ---------------- fused RMSNorm + per-token absmax int8 quant ----------------
__global__ __launch_bounds__(256) void rmsq_k(const float* __restrict__ x,
                                              const float* __restrict__ gamma,
                                              int8_t* __restrict__ qx,
                                              float* __restrict__ sxinv) {
  const int row = blockIdx.x, t = threadIdx.x;
  const float* xr = x + (size_t)row * D_DIM;
  const v4f v0 = __builtin_nontemporal_load((const v4f*)&xr[t * 4]);
  const v4f v1 = __builtin_nontemporal_load((const v4f*)&xr[1024 + t * 4]);
  double xs[8] = {v0[0], v0[1], v0[2], v0[3], v1[0], v1[1], v1[2], v1[3]};
  double ssq = 0.0;
#pragma unroll
  for (int j = 0; j < 8; ++j) ssq += xs[j] * xs[j];
  __shared__ double red[256];
  red[t] = ssq;
  __syncthreads();
  for (int st = 128; st; st >>= 1) {
    if (t < st) red[t] += red[t + st];
    __syncthreads();
  }
  const double rn = 1.0 / sqrt(red[0] / (double)D_DIM + 1e-6);
  __syncthreads();
  const float4 g0 = *(const float4*)&gamma[t * 4];
  const float4 g1 = *(const float4*)&gamma[1024 + t * 4];
  const double gs[8] = {g0.x, g0.y, g0.z, g0.w, g1.x, g1.y, g1.z, g1.w};
  double xn[8], am = 0.0;
#pragma unroll
  for (int j = 0; j < 8; ++j) {
    xn[j] = xs[j] * rn * gs[j];
    am = fmax(am, fabs(xn[j]));
  }
  red[t] = am;
  __syncthreads();
  for (int st = 128; st; st >>= 1) {
    if (t < st) red[t] = fmax(red[t], red[t + st]);
    __syncthreads();
  }
  const double amax = fmax(red[0], 1e-5);
  const double s = 127.0 / amax;
  int q[8];
#pragma unroll
  for (int j = 0; j < 8; ++j) q[j] = clampi((int)__builtin_rint(xn[j] * s), -128, 127);
  unsigned* qo = (unsigned*)(qx + (size_t)row * D_DIM);
  qo[t] = pack4i8(q[0], q[1], q[2], q[3]);
  qo[256 + t] = pack4i8(q[4], q[5], q[6], q[7]);
  if (!t) sxinv[row] = (float)(amax / 127.0);
}

// ---------------- per-token quant of gelu(h) (path A only) -------------------
__global__ __launch_bounds__(256) void hquant_k(const float* __restrict__ g,
                                                int8_t* __restrict__ qh,
                                                const unsigned* __restrict__ amaxh,
                                                float* __restrict__ shinv) {
  const int row = blockIdx.x, t = threadIdx.x;
  const float* gr = g + (size_t)row * D_HID;
  const double am = fmax((double)__uint_as_float(amaxh[row]), 1e-5);
  const double s = 127.0 / am;
  if (!t) shinv[row] = (float)(am / 127.0);
  unsigned* qo = (unsigned*)(qh + (size_t)row * D_HID);
#pragma unroll
  for (int j = 0; j < 8; ++j) {
    const v4f v = __builtin_nontemporal_load((const v4f*)&gr[j * 1024 + t * 4]);
    const int q0 = clampi((int)__builtin_rint((double)v[0] * s), -128, 127);
    const int q1 = clampi((int)__builtin_rint((double)v[1] * s), -128, 127);
    const int q2 = clampi((int)__builtin_rint((double)v[2] * s), -128, 127);
    const int q3 = clampi((int)__builtin_rint((double)v[3] * s), -128, 127);
    qo[j * 256 + t] = pack4i8(q0, q1, q2, q3);  // cached: qh is GEMM2's operand
  }
}

__global__ __launch_bounds__(256) void scalefix_k(const unsigned* __restrict__ amaxh,
                                                  float* __restrict__ shinv) {
  const int i = blockIdx.x * 256 + threadIdx.x;
  if (i < N_TOK)
    shinv[i] = (float)(fmax((double)__uint_as_float(amaxh[i]), 1e-5) / 127.0);
}

// ======== int8 NT GEMM, 256x256 tile, BK=128 (2 K-halves), 8-phase ==========
// 8 waves (2M x 4N), per-wave 128x64 = acc[8][4]. LDS 128 KiB: regions
// {A,B} x {buf0,1} x {half0,1}, each 16 KiB = 16 subblocks of 1024B.
// Subblock slot s: row s>>2, kchunk (s&3)^((s>>3)&3) (conflict-free reads,
// coalesced 4rows-x-64B staging; SQ_LDS_BANK_CONFLICT = 0 verified R5/R6).
// Counted vmcnt(8): queue holds 12 halves at peak, never drains in main loop.
// Streaming outputs use non-temporal stores so the 32-80 MiB i8 operand set
// stays L2/L3-resident (R6: g's 256 MiB write-allocate stream evicted inputs,
// FETCH 272 MB -> vmcnt waits hit HBM latency).
// EPI: 0 gelu rowmax; 1 gelu + f32 nt-store + rowmax; 2 dequant nt-store;
//      3 gelu + i8 quant store.
template <int EPI>
__global__ __launch_bounds__(512, 2) void gemm8_i8_k(const int8_t* __restrict__ A,
                                                     const int8_t* __restrict__ B, int K,
                                                     int NB_X,
                                                     float* __restrict__ Cf,
                                                     int8_t* __restrict__ Cq, int ldc,
                                                     const float* __restrict__ rowf,
                                                     const float* __restrict__ wscp,
                                                     unsigned* __restrict__ amax) {
  __shared__ __align__(16) int8_t L[131072];
  const int tid = threadIdx.x;
  const int wave = tid >> 6, lane = tid & 63;
  const int hi = lane >> 4, lo = lane & 15;
  const int wr = wave >> 2, wc = wave & 3;

  const int nwg = gridDim.x;  // multiple of 8 for both grids
  int bid = blockIdx.x;
  bid = (bid & 7) * (nwg >> 3) + (bid >> 3);
  const int bx = bid % NB_X, by = bid / NB_X;
  const int row0 = by * 256, col0 = bx * 256;

  const int srow = lane >> 2;
  const int skb = ((lane & 3) ^ ((lane >> 3) & 3)) * 16;
  const size_t aR0 = (size_t)(row0 + wave * 16 + srow) * K + skb;
  const size_t aR1 = (size_t)(row0 + (8 + wave) * 16 + srow) * K + skb;
  const size_t bR0 = (size_t)(col0 + wave * 16 + srow) * K + skb;
  const size_t bR1 = (size_t)(col0 + (8 + wave) * 16 + srow) * K + skb;
  const int NT = K >> 7;

  v4i acc[8][4];
#pragma unroll
  for (int m = 0; m < 8; ++m)
#pragma unroll
    for (int n = 0; n < 4; ++n) acc[m][n] = (v4i){0, 0, 0, 0};

  const int roff = lo * 64 + ((hi ^ ((lo >> 1) & 3)) * 16);

#define AREG(buf, h) (((buf) * 2 + (h)) * 16384)
#define BREG(buf, h) (65536 + ((buf) * 2 + (h)) * 16384)
#define STG_A(buf, h, TT)                                                      \
  do {                                                                         \
    const int tt_ = ((TT) < NT - 1) ? (TT) : (NT - 1);                         \
    const size_t ko_ = (size_t)tt_ * 128 + (size_t)(h) * 64;                   \
    gload16(A + aR0 + ko_, &L[AREG(buf, h) + wave * 1024]);                    \
    gload16(A + aR1 + ko_, &L[AREG(buf, h) + (8 + wave) * 1024]);              \
  } while (0)
#define STG_B(buf, h, TT)                                                      \
  do {                                                                         \
    const int tt_ = ((TT) < NT - 1) ? (TT) : (NT - 1);                         \
    const size_t ko_ = (size_t)tt_ * 128 + (size_t)(h) * 64;                   \
    gload16(B + bR0 + ko_, &L[BREG(buf, h) + wave * 1024]);                    \
    gload16(B + bR1 + ko_, &L[BREG(buf, h) + (8 + wave) * 1024]);              \
  } while (0)
#define DS_LO(buf, h)                                                          \
  af0 = *(const v4i*)&L[AREG(buf, h) + (wr * 8 + 0) * 1024 + roff];            \
  af1 = *(const v4i*)&L[AREG(buf, h) + (wr * 8 + 1) * 1024 + roff];            \
  af2 = *(const v4i*)&L[AREG(buf, h) + (wr * 8 + 2) * 1024 + roff];            \
  af3 = *(const v4i*)&L[AREG(buf, h) + (wr * 8 + 3) * 1024 + roff];            \
  bf0 = *(const v4i*)&L[BREG(buf, h) + (wc * 4 + 0) * 1024 + roff];            \
  bf1 = *(const v4i*)&L[BREG(buf, h) + (wc * 4 + 1) * 1024 + roff];            \
  bf2 = *(const v4i*)&L[BREG(buf, h) + (wc * 4 + 2) * 1024 + roff];            \
  bf3 = *(const v4i*)&L[BREG(buf, h) + (wc * 4 + 3) * 1024 + roff];
#define DS_HI(buf, h)                                                          \
  af0 = *(const v4i*)&L[AREG(buf, h) + (wr * 8 + 4) * 1024 + roff];            \
  af1 = *(const v4i*)&L[AREG(buf, h) + (wr * 8 + 5) * 1024 + roff];            \
  af2 = *(const v4i*)&L[AREG(buf, h) + (wr * 8 + 6) * 1024 + roff];            \
  af3 = *(const v4i*)&L[AREG(buf, h) + (wr * 8 + 7) * 1024 + roff];
#define MFMA16(mb)                                                             \
  __builtin_amdgcn_s_setprio(1);                                               \
  acc[mb + 0][0] = __builtin_amdgcn_mfma_i32_16x16x64_i8(af0, bf0, acc[mb + 0][0], 0, 0, 0); \
  acc[mb + 0][1] = __builtin_amdgcn_mfma_i32_16x16x64_i8(af0, bf1, acc[mb + 0][1], 0, 0, 0); \
  acc[mb + 0][2] = __builtin_amdgcn_mfma_i32_16x16x64_i8(af0, bf2, acc[mb + 0][2], 0, 0, 0); \
  acc[mb + 0][3] = __builtin_amdgcn_mfma_i32_16x16x64_i8(af0, bf3, acc[mb + 0][3], 0, 0, 0); \
  acc[mb + 1][0] = __builtin_amdgcn_mfma_i32_16x16x64_i8(af1, bf0, acc[mb + 1][0], 0, 0, 0); \
  acc[mb + 1][1] = __builtin_amdgcn_mfma_i32_16x16x64_i8(af1, bf1, acc[mb + 1][1], 0, 0, 0); \
  acc[mb + 1][2] = __builtin_amdgcn_mfma_i32_16x16x64_i8(af1, bf2, acc[mb + 1][2], 0, 0, 0); \
  acc[mb + 1][3] = __builtin_amdgcn_mfma_i32_16x16x64_i8(af1, bf3, acc[mb + 1][3], 0, 0, 0); \
  acc[mb + 2][0] = __builtin_amdgcn_mfma_i32_16x16x64_i8(af2, bf0, acc[mb + 2][0], 0, 0, 0); \
  acc[mb + 2][1] = __builtin_amdgcn_mfma_i32_16x16x64_i8(af2, bf1, acc[mb + 2][1], 0, 0, 0); \
  acc[mb + 2][2] = __builtin_amdgcn_mfma_i32_16x16x64_i8(af2, bf2, acc[mb + 2][2], 0, 0, 0); \
  acc[mb + 2][3] = __builtin_amdgcn_mfma_i32_16x16x64_i8(af2, bf3, acc[mb + 2][3], 0, 0, 0); \
  acc[mb + 3][0] = __builtin_amdgcn_mfma_i32_16x16x64_i8(af3, bf0, acc[mb + 3][0], 0, 0, 0); \
  acc[mb + 3][1] = __builtin_amdgcn_mfma_i32_16x16x64_i8(af3, bf1, acc[mb + 3][1], 0, 0, 0); \
  acc[mb + 3][2] = __builtin_amdgcn_mfma_i32_16x16x64_i8(af3, bf2, acc[mb + 3][2], 0, 0, 0); \
  acc[mb + 3][3] = __builtin_amdgcn_mfma_i32_16x16x64_i8(af3, bf3, acc[mb + 3][3], 0, 0, 0); \
  __builtin_amdgcn_s_setprio(0);
#define BAR1 __builtin_amdgcn_s_barrier();  // compiler inserts lgkmcnt waits
#define BAR2N __builtin_amdgcn_s_barrier();
#define BAR2V                                                                  \
  asm volatile("s_waitcnt vmcnt(8)" ::: "memory");                             \
  __builtin_amdgcn_s_barrier();

  // prologue: queue = [Ah0(0),Bh0(0),Ah1(0),Bh1(0),Ah0(1),Bh0(1)]
  STG_A(0, 0, 0);
  STG_B(0, 0, 0);
  STG_A(0, 1, 0);
  STG_B(0, 1, 0);
  STG_A(1, 0, 1);
  STG_B(1, 0, 1);
  asm volatile("s_waitcnt vmcnt(8)" ::: "memory");
  __builtin_amdgcn_s_barrier();

  const int NITER = NT >> 1;
#pragma unroll 1
  for (int it = 0; it < NITER; ++it) {
    const int T = it * 2;
    v4i af0, af1, af2, af3, bf0, bf1, bf2, bf3;
    DS_LO(0, 0); STG_A(1, 1, T + 1); BAR1; MFMA16(0); BAR2N;      // P1
    DS_HI(0, 0); STG_B(1, 1, T + 1); BAR1; MFMA16(4); BAR2V;      // P2
    DS_LO(0, 1); STG_A(0, 0, T + 2); BAR1; MFMA16(0); BAR2N;      // P3
    DS_HI(0, 1); STG_B(0, 0, T + 2); BAR1; MFMA16(4); BAR2V;      // P4
    DS_LO(1, 0); STG_A(0, 1, T + 2); BAR1; MFMA16(0); BAR2N;      // P5
    DS_HI(1, 0); STG_B(0, 1, T + 2); BAR1; MFMA16(4); BAR2V;      // P6
    DS_LO(1, 1); STG_A(1, 0, T + 3); BAR1; MFMA16(0); BAR2N;      // P7
    DS_HI(1, 1); STG_B(1, 0, T + 3); BAR1; MFMA16(4); BAR2V;      // P8
  }
  asm volatile("s_waitcnt vmcnt(0)" ::: "memory");

  // ---- epilogue ----
  const float mw = wscp[0];
#pragma unroll
  for (int m = 0; m < 8; ++m) {
#pragma unroll
    for (int r = 0; r < 4; ++r) {
      const int grow = row0 + wr * 128 + m * 16 + hi * 4 + r;
      const float f = rowf[grow] * mw;
      if constexpr (EPI == 0 || EPI == 1) {
        float rmax = 0.f;
#pragma unroll
        for (int n = 0; n < 4; ++n) {
          const int gcol = col0 + wc * 64 + n * 16 + lo;
          const float c = (float)acc[m][n][r] * f;
          const float gv = gelu_fast(c);
          if constexpr (EPI == 1)
            __builtin_nontemporal_store(gv, &Cf[(size_t)grow * ldc + gcol]);
          rmax = fmaxf(rmax, fabsf(gv));
        }
#pragma unroll
        for (int sh = 1; sh < 16; sh <<= 1) rmax = fmaxf(rmax, __shfl_xor(rmax, sh));
        if (lo == 0) atomicMax(&amax[grow], __float_as_uint(rmax));
      } else if constexpr (EPI == 3) {
        const double s = 127.0 / fmax((double)__uint_as_float(amax[grow]), 1e-5);
#pragma unroll
        for (int n = 0; n < 4; ++n) {
          const int gcol = col0 + wc * 64 + n * 16 + lo;
          const float c = (float)acc[m][n][r] * f;
          const float gv = gelu_fast(c);
          Cq[(size_t)grow * ldc + gcol] =
              (int8_t)clampi((int)__builtin_rint((double)gv * s), -128, 127);
        }
      } else {
#pragma unroll
        for (int n = 0; n < 4; ++n) {
          const int gcol = col0 + wc * 64 + n * 16 + lo;
          __builtin_nontemporal_store((float)acc[m][n][r] * f,
                                      &Cf[(size_t)grow * ldc + gcol]);
        }
      }
    }
  }
}

__global__ void fill_k(float* p, int n, float v) {
  int i = blockIdx.x * 256 + threadIdx.x;
  if (i < n) p[i] = v;
}

extern "C" void kernel_launch(void* const* d_in, const int* in_sizes, int n_in, void* d_out,
                              int out_size, void* d_ws, size_t ws_size, hipStream_t stream) {
  const float* x = (const float*)d_in[0];
  const float* w1 = (const float*)d_in[1];
  const float* w2 = (const float*)d_in[2];
  const float* gamma = (const float*)d_in[3];
  float* out = (float*)d_out;
  char* ws = (char*)d_ws;

  const size_t SQX = (size_t)N_TOK * D_DIM;
  const size_t SQW1 = (size_t)D_HID * D_DIM;
  const size_t SQW2 = (size_t)D_DIM * D_HID;
  const size_t SQH = (size_t)N_TOK * D_HID;
  const size_t SG = (size_t)N_TOK * D_HID * 4;

  size_t off = 0;
  int8_t* qx = (int8_t*)(ws + off);  off += SQX;
  int8_t* qw1 = (int8_t*)(ws + off); off += SQW1;
  int8_t* qw2 = (int8_t*)(ws + off); off += SQW2;
  int8_t* qh = (int8_t*)(ws + off);  off += SQH;
  float* sxinv = (float*)(ws + off);       off += (size_t)N_TOK * 4;
  unsigned* amaxh = (unsigned*)(ws + off); off += (size_t)N_TOK * 4;
  float* shinv = (float*)(ws + off);       off += (size_t)N_TOK * 4;
  double* wpart = (double*)(ws + off);     off += 2048 * 8;
  double* swd = (double*)(ws + off);       off += 2 * 8;
  float* wsc = (float*)(ws + off);         off += 2 * 4;
  const size_t needB = off;
  float* g = (float*)(ws + off);
  const size_t needA = off + SG;

  if (ws_size < needB) {
    const float v = 100000.0f + (float)(ws_size >> 20);
    fill_k<<<(out_size + 255) / 256, 256, 0, stream>>>(out, out_size, v);
    return;
  }
  const bool pathA = (ws_size >= needA);

  hipMemsetAsync(amaxh, 0, (size_t)N_TOK * 4, stream);
  wsum_k<<<2048, 256, 0, stream>>>(w1, w2, wpart);
  wfinal_k<<<1, 256, 0, stream>>>(wpart, swd, wsc);
  wquant_k<<<16384, 256, 0, stream>>>(w1, qw1, swd, 0);
  wquant_k<<<16384, 256, 0, stream>>>(w2, qw2, swd, 1);
  rmsq_k<<<N_TOK, 256, 0, stream>>>(x, gamma, qx, sxinv);

  const int nwg1 = (N_TOK / 256) * (D_HID / 256);  // 1024
  const int nwg2 = (N_TOK / 256) * (D_DIM / 256);  // 256
  if (pathA) {
    gemm8_i8_k<1><<<nwg1, 512, 0, stream>>>(qx, qw1, D_DIM, D_HID / 256, g, nullptr,
                                            D_HID, sxinv, wsc + 0, amaxh);
    hquant_k<<<N_TOK, 256, 0, stream>>>(g, qh, amaxh, shinv);
  } else {
    gemm8_i8_k<0><<<nwg1, 512, 0, stream>>>(qx, qw1, D_DIM, D_HID / 256, nullptr, nullptr,
                                            D_HID, sxinv, wsc + 0, amaxh);
    scalefix_k<<<(N_TOK + 255) / 256, 256, 0, stream>>>(amaxh, shinv);
    gemm8_i8_k<3><<<nwg1, 512, 0, stream>>>(qx, qw1, D_DIM, D_HID / 256, nullptr, qh,
                                            D_HID, sxinv, wsc + 0, amaxh);
  }
  gemm8_i8_k<2><<<nwg2, 512, 0, stream>>>(qh, qw2, D_HID, D_DIM / 256, out, nullptr,
                                          D_DIM, shinv, wsc + 1, nullptr);
}

// Round 9
// 607.353 us; speedup vs baseline: 1.0126x; 1.0126x over previous
//
#include <hip/hip_runtime.h>
#include <cstdint>
#include <cstddef>

#define D_DIM 2048
#define D_HID 8192
#define N_TOK 8192

typedef int v4i __attribute__((ext_vector_type(4)));
typedef float v4f __attribute__((ext_vector_type(4)));

__device__ __forceinline__ void gload16(const void* g, void* l) {
  __builtin_amdgcn_global_load_lds(
      (__attribute__((address_space(1))) void*)(void*)(const_cast<void*>(g)),
      (__attribute__((address_space(3))) void*)(void*)(l), 16, 0, 0);
}

__device__ __forceinline__ unsigned pack4i8(int a, int b, int c, int d) {
  return (unsigned)(a & 255) | ((unsigned)(b & 255) << 8) |
         ((unsigned)(c & 255) << 16) | ((unsigned)(d & 255) << 24);
}

__device__ __forceinline__ int clampi(int v, int lo, int hi) {
  return v < lo ? lo : (v > hi ? hi : v);
}

// Branch-free exact-GELU via Abramowitz-Stegun 7.1.26 erf (|eps| <= 1.5e-7 abs).
__device__ __forceinline__ float gelu_fast(float c) {
  const float ax = fabsf(c) * 0.70710678118654752440f;
  const float t = 1.0f / fmaf(0.3275911f, ax, 1.0f);
  const float poly =
      t * fmaf(t, fmaf(t, fmaf(t, fmaf(t, 1.061405429f, -1.453152027f),
                               1.421413741f), -0.284496736f), 0.254829592f);
  const float e = 1.0f - poly * __expf(-ax * ax);
  const float es = copysignf(e, c);
  return 0.5f * c * (1.0f + es);
}

// ---------------- weight |w| sum (fixed-order f64, deterministic) ------------
__global__ __launch_bounds__(256) void wsum_k(const float* __restrict__ w1,
                                              const float* __restrict__ w2,
                                              double* __restrict__ part) {
  const int b = blockIdx.x;
  const float* w = (b < 1024) ? w1 : w2;
  const size_t base = (size_t)(b & 1023) * 16384;
  const int t = threadIdx.x;
  double s = 0.0;
  for (int i = 0; i < 64; ++i) s += fabs((double)w[base + (size_t)i * 256 + t]);
  __shared__ double red[256];
  red[t] = s;
  __syncthreads();
  for (int st = 128; st; st >>= 1) {
    if (t < st) red[t] += red[t + st];
    __syncthreads();
  }
  if (!t) part[b] = red[0];
}

__global__ __launch_bounds__(256) void wfinal_k(const double* __restrict__ part,
                                                double* __restrict__ swd,
                                                float* __restrict__ wsc) {
  __shared__ double red[256];
  const int t = threadIdx.x;
  for (int m = 0; m < 2; ++m) {
    double s = part[m * 1024 + t] + part[m * 1024 + 256 + t] +
               part[m * 1024 + 512 + t] + part[m * 1024 + 768 + t];
    red[t] = s;
    __syncthreads();
    for (int st = 128; st; st >>= 1) {
      if (t < st) red[t] += red[t + st];
      __syncthreads();
    }
    if (!t) {
      double mean = red[0] / 16777216.0;
      double m2 = fmax(mean, 1e-5);
      swd[m] = 1.0 / m2;
      wsc[m] = (float)m2;
    }
    __syncthreads();
  }
}

// ---------------- ternary weight quant (f64 decision, half-even) -------------
__global__ __launch_bounds__(256) void wquant_k(const float* __restrict__ w,
                                                int8_t* __restrict__ q,
                                                const double* __restrict__ swd, int idx) {
  const double s = swd[idx];
  const size_t i = ((size_t)blockIdx.x * 256 + threadIdx.x) * 4;
  const float4 v = *(const float4*)&w[i];
  const int q0 = clampi((int)__builtin_rint((double)v.x * s), -1, 1);
  const int q1 = clampi((int)__builtin_rint((double)v.y * s), -1, 1);
  const int q2 = clampi((int)__builtin_rint((double)v.z * s), -1, 1);
  const int q3 = clampi((int)__builtin_rint((double)v.w * s), -1, 1);
  *(unsigned*)&q[i] = pack4i8(q0, q1, q2, q3);
}

// ---------------- fused RMSNorm + per-token absmax int8 quant ----------------
__global__ __launch_bounds__(256) void rmsq_k(const float* __restrict__ x,
                                              const float* __restrict__ gamma,
                                              int8_t* __restrict__ qx,
                                              float* __restrict__ sxinv) {
  const int row = blockIdx.x, t = threadIdx.x;
  const float* xr = x + (size_t)row * D_DIM;
  const v4f v0 = __builtin_nontemporal_load((const v4f*)&xr[t * 4]);
  const v4f v1 = __builtin_nontemporal_load((const v4f*)&xr[1024 + t * 4]);
  double xs[8] = {v0[0], v0[1], v0[2], v0[3], v1[0], v1[1], v1[2], v1[3]};
  double ssq = 0.0;
#pragma unroll
  for (int j = 0; j < 8; ++j) ssq += xs[j] * xs[j];
  __shared__ double red[256];
  red[t] = ssq;
  __syncthreads();
  for (int st = 128; st; st >>= 1) {
    if (t < st) red[t] += red[t + st];
    __syncthreads();
  }
  const double rn = 1.0 / sqrt(red[0] / (double)D_DIM + 1e-6);
  __syncthreads();
  const float4 g0 = *(const float4*)&gamma[t * 4];
  const float4 g1 = *(const float4*)&gamma[1024 + t * 4];
  const double gs[8] = {g0.x, g0.y, g0.z, g0.w, g1.x, g1.y, g1.z, g1.w};
  double xn[8], am = 0.0;
#pragma unroll
  for (int j = 0; j < 8; ++j) {
    xn[j] = xs[j] * rn * gs[j];
    am = fmax(am, fabs(xn[j]));
  }
  red[t] = am;
  __syncthreads();
  for (int st = 128; st; st >>= 1) {
    if (t < st) red[t] = fmax(red[t], red[t + st]);
    __syncthreads();
  }
  const double amax = fmax(red[0], 1e-5);
  const double s = 127.0 / amax;
  int q[8];
#pragma unroll
  for (int j = 0; j < 8; ++j) q[j] = clampi((int)__builtin_rint(xn[j] * s), -128, 127);
  unsigned* qo = (unsigned*)(qx + (size_t)row * D_DIM);
  qo[t] = pack4i8(q[0], q[1], q[2], q[3]);
  qo[256 + t] = pack4i8(q[4], q[5], q[6], q[7]);
  if (!t) sxinv[row] = (float)(amax / 127.0);
}

// ---------------- per-token quant of gelu(h) (path A only) -------------------
__global__ __launch_bounds__(256) void hquant_k(const float* __restrict__ g,
                                                int8_t* __restrict__ qh,
                                                const unsigned* __restrict__ amaxh,
                                                float* __restrict__ shinv) {
  const int row = blockIdx.x, t = threadIdx.x;
  const float* gr = g + (size_t)row * D_HID;
  const double am = fmax((double)__uint_as_float(amaxh[row]), 1e-5);
  const double s = 127.0 / am;
  if (!t) shinv[row] = (float)(am / 127.0);
  unsigned* qo = (unsigned*)(qh + (size_t)row * D_HID);
#pragma unroll
  for (int j = 0; j < 8; ++j) {
    const v4f v = __builtin_nontemporal_load((const v4f*)&gr[j * 1024 + t * 4]);
    const int q0 = clampi((int)__builtin_rint((double)v[0] * s), -128, 127);
    const int q1 = clampi((int)__builtin_rint((double)v[1] * s), -128, 127);
    const int q2 = clampi((int)__builtin_rint((double)v[2] * s), -128, 127);
    const int q3 = clampi((int)__builtin_rint((double)v[3] * s), -128, 127);
    qo[j * 256 + t] = pack4i8(q0, q1, q2, q3);
  }
}

__global__ __launch_bounds__(256) void scalefix_k(const unsigned* __restrict__ amaxh,
                                                  float* __restrict__ shinv) {
  const int i = blockIdx.x * 256 + threadIdx.x;
  if (i < N_TOK)
    shinv[i] = (float)(fmax((double)__uint_as_float(amaxh[i]), 1e-5) / 127.0);
}

// ==== int8 NT GEMM, 256x256, BK=128, 8-phase, REGISTER-PIPELINED frags =======
// 8 waves (2M x 4N), per-wave 128x64 = acc[8][4]. LDS 128 KiB: regions
// {A,B} x {buf0,1} x {half0,1}, each 16 KiB = 16 subblocks of 1024B.
// Subblock slot s: row s>>2, kchunk (s&3)^((s>>3)&3)  (SQ_LDS_BANK_CONFLICT=0).
// KEY CHANGE vs R8: each phase ISSUES the NEXT phase's ds_reads into an
// alternate register bank (afX/afY per phase, bfP/bfQ per LO phase), then
// barriers, then MFMAs on the bank read LAST phase -> LDS drain overlaps MFMA,
// compiler lgkmcnt for the MFMA bank is ~free (issued a full phase earlier).
// One barrier per phase. Stages are A+B pairs at odd phases with vmcnt(8):
// FIFO lands exactly the pair the next phase's pre-read needs (derived):
//   P1 stg(1,1,T+1) vm8 -> lands (0,1)@T   (read P2, MFMA P3/P4)
//   P3 stg(0,0,T+2) vm8 -> lands (1,0)@T+1 (read P4, MFMA P5/P6)
//   P5 stg(0,1,T+2) vm8 -> lands (1,1)@T+1 (read P6, MFMA P7/P8)
//   P7 stg(1,0,T+3) vm8 -> lands (0,0)@T+2 (read P8, MFMA next P1/P2)
// EPI: 0 gelu rowmax; 1 gelu + f32 nt-store + rowmax; 2 dequant nt-store;
//      3 gelu + i8 quant store.
template <int EPI>
__global__ __launch_bounds__(512, 2) void gemm8_i8_k(const int8_t* __restrict__ A,
                                                     const int8_t* __restrict__ B, int K,
                                                     int NB_X,
                                                     float* __restrict__ Cf,
                                                     int8_t* __restrict__ Cq, int ldc,
                                                     const float* __restrict__ rowf,
                                                     const float* __restrict__ wscp,
                                                     unsigned* __restrict__ amax) {
  __shared__ __align__(16) int8_t L[131072];
  const int tid = threadIdx.x;
  const int wave = tid >> 6, lane = tid & 63;
  const int hi = lane >> 4, lo = lane & 15;
  const int wr = wave >> 2, wc = wave & 3;

  const int nwg = gridDim.x;  // multiple of 8 for both grids
  int bid = blockIdx.x;
  bid = (bid & 7) * (nwg >> 3) + (bid >> 3);
  const int bx = bid % NB_X, by = bid / NB_X;
  const int row0 = by * 256, col0 = bx * 256;

  const int srow = lane >> 2;
  const int skb = ((lane & 3) ^ ((lane >> 3) & 3)) * 16;
  const size_t aR0 = (size_t)(row0 + wave * 16 + srow) * K + skb;
  const size_t aR1 = (size_t)(row0 + (8 + wave) * 16 + srow) * K + skb;
  const size_t bR0 = (size_t)(col0 + wave * 16 + srow) * K + skb;
  const size_t bR1 = (size_t)(col0 + (8 + wave) * 16 + srow) * K + skb;
  const int NT = K >> 7;

  v4i acc[8][4];
#pragma unroll
  for (int m = 0; m < 8; ++m)
#pragma unroll
    for (int n = 0; n < 4; ++n) acc[m][n] = (v4i){0, 0, 0, 0};

  const int roff = lo * 64 + ((hi ^ ((lo >> 1) & 3)) * 16);

#define AREG(buf, h) (((buf) * 2 + (h)) * 16384)
#define BREG(buf, h) (65536 + ((buf) * 2 + (h)) * 16384)
#define STG_AB(buf, h, TT)                                                     \
  do {                                                                         \
    const int tt_ = ((TT) < NT - 1) ? (TT) : (NT - 1);                         \
    const size_t ko_ = (size_t)tt_ * 128 + (size_t)(h) * 64;                   \
    gload16(A + aR0 + ko_, &L[AREG(buf, h) + wave * 1024]);                    \
    gload16(A + aR1 + ko_, &L[AREG(buf, h) + (8 + wave) * 1024]);              \
    gload16(B + bR0 + ko_, &L[BREG(buf, h) + wave * 1024]);                    \
    gload16(B + bR1 + ko_, &L[BREG(buf, h) + (8 + wave) * 1024]);              \
  } while (0)
// read A subblocks (base..base+3) of region into 4 named regs
#define RD_A(buf, h, base, r0, r1, r2, r3)                                     \
  r0 = *(const v4i*)&L[AREG(buf, h) + (wr * 8 + base + 0) * 1024 + roff];      \
  r1 = *(const v4i*)&L[AREG(buf, h) + (wr * 8 + base + 1) * 1024 + roff];      \
  r2 = *(const v4i*)&L[AREG(buf, h) + (wr * 8 + base + 2) * 1024 + roff];      \
  r3 = *(const v4i*)&L[AREG(buf, h) + (wr * 8 + base + 3) * 1024 + roff];
#define RD_B(buf, h, r0, r1, r2, r3)                                           \
  r0 = *(const v4i*)&L[BREG(buf, h) + (wc * 4 + 0) * 1024 + roff];             \
  r1 = *(const v4i*)&L[BREG(buf, h) + (wc * 4 + 1) * 1024 + roff];             \
  r2 = *(const v4i*)&L[BREG(buf, h) + (wc * 4 + 2) * 1024 + roff];             \
  r3 = *(const v4i*)&L[BREG(buf, h) + (wc * 4 + 3) * 1024 + roff];
#define MFMA16(mb, a0, a1, a2, a3, b0, b1, b2, b3)                             \
  __builtin_amdgcn_s_setprio(1);                                               \
  acc[mb + 0][0] = __builtin_amdgcn_mfma_i32_16x16x64_i8(a0, b0, acc[mb + 0][0], 0, 0, 0); \
  acc[mb + 0][1] = __builtin_amdgcn_mfma_i32_16x16x64_i8(a0, b1, acc[mb + 0][1], 0, 0, 0); \
  acc[mb + 0][2] = __builtin_amdgcn_mfma_i32_16x16x64_i8(a0, b2, acc[mb + 0][2], 0, 0, 0); \
  acc[mb + 0][3] = __builtin_amdgcn_mfma_i32_16x16x64_i8(a0, b3, acc[mb + 0][3], 0, 0, 0); \
  acc[mb + 1][0] = __builtin_amdgcn_mfma_i32_16x16x64_i8(a1, b0, acc[mb + 1][0], 0, 0, 0); \
  acc[mb + 1][1] = __builtin_amdgcn_mfma_i32_16x16x64_i8(a1, b1, acc[mb + 1][1], 0, 0, 0); \
  acc[mb + 1][2] = __builtin_amdgcn_mfma_i32_16x16x64_i8(a1, b2, acc[mb + 1][2], 0, 0, 0); \
  acc[mb + 1][3] = __builtin_amdgcn_mfma_i32_16x16x64_i8(a1, b3, acc[mb + 1][3], 0, 0, 0); \
  acc[mb + 2][0] = __builtin_amdgcn_mfma_i32_16x16x64_i8(a2, b0, acc[mb + 2][0], 0, 0, 0); \
  acc[mb + 2][1] = __builtin_amdgcn_mfma_i32_16x16x64_i8(a2, b1, acc[mb + 2][1], 0, 0, 0); \
  acc[mb + 2][2] = __builtin_amdgcn_mfma_i32_16x16x64_i8(a2, b2, acc[mb + 2][2], 0, 0, 0); \
  acc[mb + 2][3] = __builtin_amdgcn_mfma_i32_16x16x64_i8(a2, b3, acc[mb + 2][3], 0, 0, 0); \
  acc[mb + 3][0] = __builtin_amdgcn_mfma_i32_16x16x64_i8(a3, b0, acc[mb + 3][0], 0, 0, 0); \
  acc[mb + 3][1] = __builtin_amdgcn_mfma_i32_16x16x64_i8(a3, b1, acc[mb + 3][1], 0, 0, 0); \
  acc[mb + 3][2] = __builtin_amdgcn_mfma_i32_16x16x64_i8(a3, b2, acc[mb + 3][2], 0, 0, 0); \
  acc[mb + 3][3] = __builtin_amdgcn_mfma_i32_16x16x64_i8(a3, b3, acc[mb + 3][3], 0, 0, 0); \
  __builtin_amdgcn_s_setprio(0);
#define VM8 asm volatile("s_waitcnt vmcnt(8)" ::: "memory");
#define BAR __builtin_amdgcn_s_barrier();

  // fragment banks (statically named; live across phases)
  v4i aX0, aX1, aX2, aX3, aY0, aY1, aY2, aY3;
  v4i bP0, bP1, bP2, bP3, bQ0, bQ1, bQ2, bQ3;

  // ---- prologue ----
  STG_AB(0, 0, 0);
  asm volatile("s_waitcnt vmcnt(0)" ::: "memory");
  BAR;                               // (0,0)@0 published
  RD_A(0, 0, 0, aX0, aX1, aX2, aX3)  // LO(0,0) -> X,P (for P1's MFMA)
  RD_B(0, 0, bP0, bP1, bP2, bP3)
  STG_AB(0, 1, 0);                   // queue: (0,1)@0
  STG_AB(1, 0, 1);                   // queue: +(1,0)@1  -> 8 gloads outstanding

  const int NITER = NT >> 1;
#pragma unroll 1
  for (int it = 0; it < NITER; ++it) {
    const int T = it * 2;
    // P1: stage (1,1)@T+1 | vm8 lands (0,1)@T | read HI(0,0)->Y | MFMA LO(0,0)
    STG_AB(1, 1, T + 1);
    RD_A(0, 0, 4, aY0, aY1, aY2, aY3)
    VM8; BAR;
    MFMA16(0, aX0, aX1, aX2, aX3, bP0, bP1, bP2, bP3);
    // P2: read LO(0,1)->X,Q | MFMA HI(0,0)
    RD_A(0, 1, 0, aX0, aX1, aX2, aX3)
    RD_B(0, 1, bQ0, bQ1, bQ2, bQ3)
    BAR;
    MFMA16(4, aY0, aY1, aY2, aY3, bP0, bP1, bP2, bP3);
    // P3: stage (0,0)@T+2 | vm8 lands (1,0)@T+1 | read HI(0,1)->Y | MFMA LO(0,1)
    STG_AB(0, 0, T + 2);
    RD_A(0, 1, 4, aY0, aY1, aY2, aY3)
    VM8; BAR;
    MFMA16(0, aX0, aX1, aX2, aX3, bQ0, bQ1, bQ2, bQ3);
    // P4: read LO(1,0)->X,P | MFMA HI(0,1)
    RD_A(1, 0, 0, aX0, aX1, aX2, aX3)
    RD_B(1, 0, bP0, bP1, bP2, bP3)
    BAR;
    MFMA16(4, aY0, aY1, aY2, aY3, bQ0, bQ1, bQ2, bQ3);
    // P5: stage (0,1)@T+2 | vm8 lands (1,1)@T+1 | read HI(1,0)->Y | MFMA LO(1,0)
    STG_AB(0, 1, T + 2);
    RD_A(1, 0, 4, aY0, aY1, aY2, aY3)
    VM8; BAR;
    MFMA16(0, aX0, aX1, aX2, aX3, bP0, bP1, bP2, bP3);
    // P6: read LO(1,1)->X,Q | MFMA HI(1,0)
    RD_A(1, 1, 0, aX0, aX1, aX2, aX3)
    RD_B(1, 1, bQ0, bQ1, bQ2, bQ3)
    BAR;
    MFMA16(4, aY0, aY1, aY2, aY3, bP0, bP1, bP2, bP3);
    // P7: stage (1,0)@T+3 | vm8 lands (0,0)@T+2 | read HI(1,1)->Y | MFMA LO(1,1)
    STG_AB(1, 0, T + 3);
    RD_A(1, 1, 4, aY0, aY1, aY2, aY3)
    VM8; BAR;
    MFMA16(0, aX0, aX1, aX2, aX3, bQ0, bQ1, bQ2, bQ3);
    // P8: read LO(0,0)@T+2->X,P | MFMA HI(1,1)
    RD_A(0, 0, 0, aX0, aX1, aX2, aX3)
    RD_B(0, 0, bP0, bP1, bP2, bP3)
    BAR;
    MFMA16(4, aY0, aY1, aY2, aY3, bQ0, bQ1, bQ2, bQ3);
  }
  asm volatile("s_waitcnt vmcnt(0) lgkmcnt(0)" ::: "memory");

  // ---- epilogue ----
  const float mw = wscp[0];
#pragma unroll
  for (int m = 0; m < 8; ++m) {
#pragma unroll
    for (int r = 0; r < 4; ++r) {
      const int grow = row0 + wr * 128 + m * 16 + hi * 4 + r;
      const float f = rowf[grow] * mw;
      if constexpr (EPI == 0 || EPI == 1) {
        float rmax = 0.f;
#pragma unroll
        for (int n = 0; n < 4; ++n) {
          const int gcol = col0 + wc * 64 + n * 16 + lo;
          const float c = (float)acc[m][n][r] * f;
          const float gv = gelu_fast(c);
          if constexpr (EPI == 1)
            __builtin_nontemporal_store(gv, &Cf[(size_t)grow * ldc + gcol]);
          rmax = fmaxf(rmax, fabsf(gv));
        }
#pragma unroll
        for (int sh = 1; sh < 16; sh <<= 1) rmax = fmaxf(rmax, __shfl_xor(rmax, sh));
        if (lo == 0) atomicMax(&amax[grow], __float_as_uint(rmax));
      } else if constexpr (EPI == 3) {
        const double s = 127.0 / fmax((double)__uint_as_float(amax[grow]), 1e-5);
#pragma unroll
        for (int n = 0; n < 4; ++n) {
          const int gcol = col0 + wc * 64 + n * 16 + lo;
          const float c = (float)acc[m][n][r] * f;
          const float gv = gelu_fast(c);
          Cq[(size_t)grow * ldc + gcol] =
              (int8_t)clampi((int)__builtin_rint((double)gv * s), -128, 127);
        }
      } else {
#pragma unroll
        for (int n = 0; n < 4; ++n) {
          const int gcol = col0 + wc * 64 + n * 16 + lo;
          __builtin_nontemporal_store((float)acc[m][n][r] * f,
                                      &Cf[(size_t)grow * ldc + gcol]);
        }
      }
    }
  }
}

__global__ void fill_k(float* p, int n, float v) {
  int i = blockIdx.x * 256 + threadIdx.x;
  if (i < n) p[i] = v;
}

extern "C" void kernel_launch(void* const* d_in, const int* in_sizes, int n_in, void* d_out,
                              int out_size, void* d_ws, size_t ws_size, hipStream_t stream) {
  const float* x = (const float*)d_in[0];
  const float* w1 = (const float*)d_in[1];
  const float* w2 = (const float*)d_in[2];
  const float* gamma = (const float*)d_in[3];
  float* out = (float*)d_out;
  char* ws = (char*)d_ws;

  const size_t SQX = (size_t)N_TOK * D_DIM;
  const size_t SQW1 = (size_t)D_HID * D_DIM;
  const size_t SQW2 = (size_t)D_DIM * D_HID;
  const size_t SQH = (size_t)N_TOK * D_HID;
  const size_t SG = (size_t)N_TOK * D_HID * 4;

  size_t off = 0;
  int8_t* qx = (int8_t*)(ws + off);  off += SQX;
  int8_t* qw1 = (int8_t*)(ws + off); off += SQW1;
  int8_t* qw2 = (int8_t*)(ws + off); off += SQW2;
  int8_t* qh = (int8_t*)(ws + off);  off += SQH;
  float* sxinv = (float*)(ws + off);       off += (size_t)N_TOK * 4;
  unsigned* amaxh = (unsigned*)(ws + off); off += (size_t)N_TOK * 4;
  float* shinv = (float*)(ws + off);       off += (size_t)N_TOK * 4;
  double* wpart = (double*)(ws + off);     off += 2048 * 8;
  double* swd = (double*)(ws + off);       off += 2 * 8;
  float* wsc = (float*)(ws + off);         off += 2 * 4;
  const size_t needB = off;
  float* g = (float*)(ws + off);
  const size_t needA = off + SG;

  if (ws_size < needB) {
    const float v = 100000.0f + (float)(ws_size >> 20);
    fill_k<<<(out_size + 255) / 256, 256, 0, stream>>>(out, out_size, v);
    return;
  }
  const bool pathA = (ws_size >= needA);

  hipMemsetAsync(amaxh, 0, (size_t)N_TOK * 4, stream);
  wsum_k<<<2048, 256, 0, stream>>>(w1, w2, wpart);
  wfinal_k<<<1, 256, 0, stream>>>(wpart, swd, wsc);
  wquant_k<<<16384, 256, 0, stream>>>(w1, qw1, swd, 0);
  wquant_k<<<16384, 256, 0, stream>>>(w2, qw2, swd, 1);
  rmsq_k<<<N_TOK, 256, 0, stream>>>(x, gamma, qx, sxinv);

  const int nwg1 = (N_TOK / 256) * (D_HID / 256);  // 1024
  const int nwg2 = (N_TOK / 256) * (D_DIM / 256);  // 256
  if (pathA) {
    gemm8_i8_k<1><<<nwg1, 512, 0, stream>>>(qx, qw1, D_DIM, D_HID / 256, g, nullptr,
                                            D_HID, sxinv, wsc + 0, amaxh);
    hquant_k<<<N_TOK, 256, 0, stream>>>(g, qh, amaxh, shinv);
  } else {
    gemm8_i8_k<0><<<nwg1, 512, 0, stream>>>(qx, qw1, D_DIM, D_HID / 256, nullptr, nullptr,
                                            D_HID, sxinv, wsc + 0, amaxh);
    scalefix_k<<<(N_TOK + 255) / 256, 256, 0, stream>>>(amaxh, shinv);
    gemm8_i8_k<3><<<nwg1, 512, 0, stream>>>(qx, qw1, D_DIM, D_HID / 256, nullptr, qh,
                                            D_HID, sxinv, wsc + 0, amaxh);
  }
  gemm8_i8_k<2><<<nwg2, 512, 0, stream>>>(qh, qw2, D_HID, D_DIM / 256, out, nullptr,
                                          D_DIM, shinv, wsc + 1, nullptr);
}